// Round 10
// baseline (586.569 us; speedup 1.0000x reference)
//
#include <hip/hip_runtime.h>
#include <math.h>

// Problem constants
#define B_   128
#define E_   512
#define H_   512
#define S_   2048
#define V_   83
#define PAD_ 82

typedef float v4f __attribute__((ext_vector_type(4)));

__device__ __forceinline__ v4f ldnt4(const float* p) {
    return __builtin_nontemporal_load((const v4f*)p);
}

// ---- one-time prep -------------------------------------------------------

// pe2[e] = pe(e,2); x01i[e*3+{0,1,2}] = {embPAD[e]+pe(e,0), embPAD[e]+pe(e,1), 0}
__global__ void k_misc(const float* __restrict__ emb, float* __restrict__ pe2,
                       float* __restrict__ x01i) {
    int e = threadIdx.x;                              // 1 block, 512 threads
    float freq = expf(-9.210340371976184f * (float)(e & ~1) * (1.0f / 512.0f));
    float p0 = (e & 1) ? 1.0f : 0.0f;                 // cos(0)/sin(0)
    float p1 = (e & 1) ? cosf(freq) : sinf(freq);
    float p2 = (e & 1) ? cosf(2.0f * freq) : sinf(2.0f * freq);
    pe2[e] = p2;
    float ep = emb[PAD_ * 512 + e];
    x01i[e * 3 + 0] = ep + p0;
    x01i[e * 3 + 1] = ep + p1;
    x01i[e * 3 + 2] = 0.0f;
}

// bc[o] = conv_b[o] + dot(conv_w[o, 0:1536], x01i)  — contiguous rows, wave per o
__global__ void k_base3(const float* __restrict__ cw, const float* __restrict__ x01i,
                        const float* __restrict__ cb, float* __restrict__ bc) {
    int t = threadIdx.x, w = t >> 6, lane = t & 63;   // grid 256, block 256
    __shared__ float xs[1536];
    for (int j = t; j < 1536; j += 256) xs[j] = x01i[j];
    __syncthreads();
    int o = blockIdx.x * 4 + w;
    const float* rp = cw + (size_t)o * 1536 + lane * 4;
    float acc = 0.f;
    #pragma unroll
    for (int j = 0; j < 6; ++j) {
        float4 v = *(const float4*)(rp + j * 256);
        const float* xp = &xs[lane * 4 + j * 256];
        acc += v.x * xp[0] + v.y * xp[1] + v.z * xp[2] + v.w * xp[3];
    }
    #pragma unroll
    for (int off = 32; off > 0; off >>= 1) acc += __shfl_down(acc, off, 64);
    if (lane == 0) bc[o] = acc + cb[o];
}

// Wc[o*512 + e] = conv_w[o*1536 + e*3 + 2]   (compacted k=2 slice, row-major [o][e])
__global__ void k_prepc(const float* __restrict__ cw, float* __restrict__ Wc) {
    int idx = blockIdx.x * 256 + threadIdx.x;        // < 524288
    int o = idx >> 9, e = idx & 511;
    Wc[idx] = cw[o * 1536 + e * 3 + 2];
}

// ---- per-layer kernels ---------------------------------------------------

// Fused x + y + glu/d + partial scores.  grid (8 hc, 128 b), block 256 = 4 waves.
// Block owns 64 h-rows (hg = hc*64 .. +64).  Phase 1: x in LDS.  Phase 2: wave w
// computes rows w*16..w*16+16: ya/yb via 64-lane shuffle dot over Wc rows, glu, d.
// Phase 3: wave w streams ALL 64 enc rows over its own 512-wide s-slice.
__global__ void __launch_bounds__(256) k_syx(
        int first, const int* __restrict__ tok, const float* __restrict__ emb,
        const float* __restrict__ hbuf, const float* __restrict__ pe2,
        const float* __restrict__ Wc, const float* __restrict__ bc,
        const float* __restrict__ eo, float* __restrict__ glu,
        float* __restrict__ part) {
    int hc = blockIdx.x, b = blockIdx.y, t = threadIdx.x;
    int w = t >> 6, lane = t & 63;
    __shared__ float xs[512];
    __shared__ float dl[64];
    for (int e = t; e < 512; e += 256) {
        float v = first ? emb[tok[b] * 512 + e] : hbuf[b * 512 + e];
        xs[e] = v + pe2[e];
    }
    __syncthreads();
    // Phase 2: y-pairs for this wave's 16 rows
    for (int r = 0; r < 16; ++r) {
        int hg = hc * 64 + w * 16 + r;
        const float* wa = Wc + (size_t)hg * 512;
        const float* wb = Wc + (size_t)(512 + hg) * 512;
        float pa = 0.f, pb = 0.f;
        #pragma unroll
        for (int k = 0; k < 8; ++k) {
            int e = lane + k * 64;
            float x = xs[e];
            pa += wa[e] * x;
            pb += wb[e] * x;
        }
        #pragma unroll
        for (int off = 32; off > 0; off >>= 1) {
            pa += __shfl_xor(pa, off, 64);
            pb += __shfl_xor(pb, off, 64);
        }
        if (lane == 0) {
            float ya = pa + bc[hg];
            float yb = pb + bc[512 + hg];
            float g = ya / (1.0f + expf(-yb));
            glu[b * 512 + hg] = g;
            dl[w * 16 + r] = g + xs[hg];
        }
    }
    __syncthreads();
    // Phase 3: stream 64 rows, wave-private s-slice [w*512, w*512+512)
    v4f a0 = (v4f)(0.f), a1 = (v4f)(0.f);
    const float* bp = eo + ((size_t)b * 512 + hc * 64) * 2048 + w * 512 + lane * 4;
    for (int r = 0; r < 64; ++r) {
        float dh = dl[r];
        const float* rp = bp + (size_t)r * 2048;
        a0 += dh * ldnt4(rp);
        a1 += dh * ldnt4(rp + 256);
    }
    float* pp = part + (size_t)hc * 262144 + b * 2048 + w * 512 + lane * 4;
    *(v4f*)pp = a0;
    *(v4f*)(pp + 256) = a1;
}

// sum 8 partials + softmax over S=2048 per batch; block 256, v4f slots
__global__ void k_softmax2(const float* __restrict__ part, float* __restrict__ attn) {
    int b = blockIdx.x, t = threadIdx.x;              // block 256
    v4f v0 = (v4f)(0.f), v1 = (v4f)(0.f);
    #pragma unroll
    for (int hc = 0; hc < 8; ++hc) {
        const float* pp = part + (size_t)hc * 262144 + b * 2048 + t * 4;
        v0 += *(const v4f*)pp;
        v1 += *(const v4f*)(pp + 1024);
    }
    float m = fmaxf(fmaxf(fmaxf(v0[0], v0[1]), fmaxf(v0[2], v0[3])),
                    fmaxf(fmaxf(v1[0], v1[1]), fmaxf(v1[2], v1[3])));
    __shared__ float r[256];
    r[t] = m; __syncthreads();
    for (int s = 128; s > 0; s >>= 1) { if (t < s) r[t] = fmaxf(r[t], r[t + s]); __syncthreads(); }
    float M = r[0]; __syncthreads();
    v4f e0, e1;
    float sum = 0.f;
    #pragma unroll
    for (int i = 0; i < 4; ++i) { e0[i] = expf(v0[i] - M); sum += e0[i]; }
    #pragma unroll
    for (int i = 0; i < 4; ++i) { e1[i] = expf(v1[i] - M); sum += e1[i]; }
    r[t] = sum; __syncthreads();
    for (int s = 128; s > 0; s >>= 1) { if (t < s) r[t] += r[t + s]; __syncthreads(); }
    float inv = 1.0f / r[0];
    *(v4f*)&attn[b * 2048 + t * 4] = e0 * inv;
    *(v4f*)&attn[b * 2048 + 1024 + t * 4] = e1 * inv;
}

// c[b,h] = sum_s attn[b,s]*enc_total[b,h,s]; h_out = glu + c.
// block 256 = 4 waves; block owns 8 h-rows (2 per wave); attn staged in LDS once.
__global__ void k_c2(const float* __restrict__ attn, const float* __restrict__ enc,
                     const float* __restrict__ glu, float* __restrict__ hbuf) {
    int t = threadIdx.x;                              // block 256, grid 8192
    int b  = blockIdx.x >> 6;
    int h0 = (blockIdx.x & 63) << 3;
    __shared__ float al[2048];
    for (int j = t; j < 2048; j += 256) al[j] = attn[b * 2048 + j];
    __syncthreads();
    int w = t >> 6, lane = t & 63;
    int h1 = h0 + w * 2, h2 = h1 + 1;
    const float* vp1 = enc + ((size_t)b * 512 + h1) * 2048;
    const float* vp2 = enc + ((size_t)b * 512 + h2) * 2048;
    float acc1 = 0.f, acc2 = 0.f;
    #pragma unroll
    for (int it = 0; it < 8; ++it) {
        int s = it * 256 + lane * 4;
        v4f u1 = ldnt4(vp1 + s);
        v4f u2 = ldnt4(vp2 + s);
        float4 p = *(const float4*)&al[s];
        acc1 += p.x * u1[0] + p.y * u1[1] + p.z * u1[2] + p.w * u1[3];
        acc2 += p.x * u2[0] + p.y * u2[1] + p.z * u2[2] + p.w * u2[3];
    }
    #pragma unroll
    for (int off = 32; off > 0; off >>= 1) {
        acc1 += __shfl_down(acc1, off, 64);
        acc2 += __shfl_down(acc2, off, 64);
    }
    if (lane == 0) {
        hbuf[b * 512 + h1] = glu[b * 512 + h1] + acc1;
        hbuf[b * 512 + h2] = glu[b * 512 + h2] + acc2;
    }
}

// ---- epilogue (fused logits/log-softmax + softmax over H) ---------------

__global__ void k_epi(const float* __restrict__ h, const float* __restrict__ l2w,
                      const float* __restrict__ l2b, float* __restrict__ out) {
    int b = blockIdx.x, t = threadIdx.x;              // block 256
    __shared__ float hl[512];
    hl[t] = h[b * 512 + t]; hl[t + 256] = h[b * 512 + 256 + t];
    __syncthreads();
    float acc = 0.f;
    if (t < V_) {
        acc = l2b[t];
        for (int e = 0; e < 512; ++e) acc += hl[e] * l2w[t * 512 + e];
    }
    __shared__ float r[256];
    r[t] = (t < V_) ? acc : -1e30f; __syncthreads();
    for (int s = 128; s > 0; s >>= 1) { if (t < s) r[t] = fmaxf(r[t], r[t + s]); __syncthreads(); }
    float M = r[0]; __syncthreads();
    r[t] = (t < V_) ? expf(acc - M) : 0.f; __syncthreads();
    for (int s = 128; s > 0; s >>= 1) { if (t < s) r[t] += r[t + s]; __syncthreads(); }
    float L = M + logf(r[0]);
    if (t < V_) out[65536 + b * V_ + t] = acc - L;
    __syncthreads();
    float v0 = hl[t], v1 = hl[t + 256];
    r[t] = fmaxf(v0, v1); __syncthreads();
    for (int s = 128; s > 0; s >>= 1) { if (t < s) r[t] = fmaxf(r[t], r[t + s]); __syncthreads(); }
    float M2 = r[0]; __syncthreads();
    float e0 = expf(v0 - M2), e1 = expf(v1 - M2);
    r[t] = e0 + e1; __syncthreads();
    for (int s = 128; s > 0; s >>= 1) { if (t < s) r[t] += r[t + s]; __syncthreads(); }
    float inv = 1.0f / r[0];
    out[b * 512 + t] = e0 * inv;
    out[b * 512 + 256 + t] = e1 * inv;
}

// ---- launch --------------------------------------------------------------

extern "C" void kernel_launch(void* const* d_in, const int* in_sizes, int n_in,
                              void* d_out, int out_size, void* d_ws, size_t ws_size,
                              hipStream_t stream) {
    const float* enc_out = (const float*)d_in[0];   // [B,H,S] f32
    const float* enc_tot = (const float*)d_in[1];   // [B,H,S] f32
    const int*   tok     = (const int*)d_in[2];     // [B] int32
    const float* emb     = (const float*)d_in[4];   // [V,E] f32
    const float* conv_w  = (const float*)d_in[5];   // [1024,512,3] f32
    const float* conv_b  = (const float*)d_in[6];   // [1024] f32
    const float* l2w     = (const float*)d_in[7];   // [83,512] f32
    const float* l2b     = (const float*)d_in[8];   // [83] f32
    float* out = (float*)d_out;                     // 65536 + 10624 f32
    float* ws = (float*)d_ws;

    // ws layout (floats)
    float* Wc   = ws;                 // 524288  ([o][e] compact k=2 slice)
    float* bc   = Wc + 524288;        // 1024    (base + conv_b)
    float* pe2  = bc + 1024;          // 512
    float* x01i = pe2 + 512;          // 1536
    float* glu  = x01i + 1536;        // 65536
    float* part = glu + 65536;        // 8*262144 = 2097152
    float* attn = part + 2097152;     // 262144
    float* hbuf = attn + 262144;      // 65536
    // total ~12.1 MB

    k_misc<<<1, 512, 0, stream>>>(emb, pe2, x01i);
    k_base3<<<256, 256, 0, stream>>>(conv_w, x01i, conv_b, bc);
    k_prepc<<<2048, 256, 0, stream>>>(conv_w, Wc);

    for (int L = 0; L < 3; ++L) {
        k_syx<<<dim3(8, 128), 256, 0, stream>>>(L == 0 ? 1 : 0, tok, emb, hbuf, pe2,
                                                Wc, bc, enc_out, glu, part);
        k_softmax2<<<128, 256, 0, stream>>>(part, attn);
        k_c2<<<8192, 256, 0, stream>>>(attn, enc_tot, glu, hbuf);
    }

    k_epi<<<128, 256, 0, stream>>>(hbuf, l2w, l2b, out);
}